// Round 3
// baseline (839.372 us; speedup 1.0000x reference)
//
#include <hip/hip_runtime.h>
#include <hip/hip_bf16.h>
#include <cstdint>
#include <cstddef>

#define T_TOK 4096
#define DMODEL 1024
#define HIDDEN 2048
#define NEXP 8     // routed experts; index 8 = shared
#define CAPA 1408  // per-expert slot capacity (mean load 1024, sd ~30)

typedef __bf16 bf16_t;
typedef bf16_t bf16x8 __attribute__((ext_vector_type(8)));
typedef float f32x4 __attribute__((ext_vector_type(4)));

#define LGKM0() asm volatile("s_waitcnt lgkmcnt(0)" ::: "memory")
#define VMCNT8() asm volatile("s_waitcnt vmcnt(8)" ::: "memory")
#define VMCNT0() asm volatile("s_waitcnt vmcnt(0)" ::: "memory")
#define SCHED0() __builtin_amdgcn_sched_barrier(0)
#define BARRIER() __builtin_amdgcn_s_barrier()

// async global->LDS, 16B per lane; LDS dest = wave-uniform base + lane*16
__device__ __forceinline__ void gl_lds16(const void* g, void* l) {
    __builtin_amdgcn_global_load_lds(
        (const __attribute__((address_space(1))) unsigned int*)g,
        (__attribute__((address_space(3))) unsigned int*)l, 16, 0, 0);
}

// ---------------- x f32 -> bf16 (8 elts/thread, 16B stores) ----------------
__global__ __launch_bounds__(256) void cvt_x_kernel(const float* __restrict__ x,
                                                    bf16_t* __restrict__ xb, int n8) {
    int i = blockIdx.x * 256 + threadIdx.x;
    if (i >= n8) return;
    const float4* v = (const float4*)(x + (size_t)i * 8);
    float4 a = v[0], b = v[1];
    bf16x8 o = {(bf16_t)a.x, (bf16_t)a.y, (bf16_t)a.z, (bf16_t)a.w,
                (bf16_t)b.x, (bf16_t)b.y, (bf16_t)b.z, (bf16_t)b.w};
    *(bf16x8*)(xb + (size_t)i * 8) = o;
}

// ---------------- router: logits -> top2 -> expert lists + per-token pair ----------------
__global__ __launch_bounds__(256) void router_kernel(const float* __restrict__ x,
                                                     const float* __restrict__ wr,
                                                     int* __restrict__ cnt,
                                                     int* __restrict__ tok,
                                                     float* __restrict__ gate,
                                                     int2* __restrict__ pair) {
    int token = (blockIdx.x * 256 + threadIdx.x) >> 6;
    int lane = threadIdx.x & 63;
    if (token >= T_TOK) return;
    const float* xr = x + (size_t)token * DMODEL;
    float acc[8];
#pragma unroll
    for (int e = 0; e < 8; e++) acc[e] = 0.f;
    for (int d = lane; d < DMODEL; d += 64) {
        float xv = xr[d];
        const float* w = wr + d * 8;
#pragma unroll
        for (int e = 0; e < 8; e++) acc[e] += xv * w[e];
    }
#pragma unroll
    for (int e = 0; e < 8; e++) {
#pragma unroll
        for (int off = 32; off > 0; off >>= 1) acc[e] += __shfl_down(acc[e], off);
    }
    if (lane == 0) {
        int i1 = 0; float v1 = acc[0];
#pragma unroll
        for (int e = 1; e < 8; e++) if (acc[e] > v1) { v1 = acc[e]; i1 = e; }
        int i2 = -1; float v2 = -1e30f;
#pragma unroll
        for (int e = 0; e < 8; e++) if (e != i1 && acc[e] > v2) { v2 = acc[e]; i2 = e; }
        float g1 = 1.f / (1.f + __expf(v2 - v1));
        float g2 = 1.f - g1;
        int p1 = atomicAdd(&cnt[i1], 1);
        int px = -1, py = -1;
        if (p1 < CAPA) {
            tok[(size_t)i1 * CAPA + p1] = token; gate[(size_t)i1 * CAPA + p1] = g1;
            px = i1 * CAPA + p1;
        }
        int p2 = atomicAdd(&cnt[i2], 1);
        if (p2 < CAPA) {
            tok[(size_t)i2 * CAPA + p2] = token; gate[(size_t)i2 * CAPA + p2] = g2;
            py = i2 * CAPA + p2;
        }
        pair[token] = make_int2(px, py);
    }
}

// ---------------- transpose+cvt: f32 [R][C] -> bf16 [C][R], 64x64 tiles (for w2) ----------------
__global__ __launch_bounds__(256) void transpose_cvt_kernel(const float* __restrict__ w,
                                                            const float* __restrict__ sw,
                                                            bf16_t* __restrict__ out,
                                                            int R, int C) {
    __shared__ float tile[64][65];
    int z = blockIdx.z;
    const float* src = (z < NEXP) ? (w + (size_t)z * R * C) : sw;
    bf16_t* dst = out + (size_t)z * R * C;
    int c0 = blockIdx.x * 64, r0 = blockIdx.y * 64;
    int t = threadIdx.x;
    int lr = t >> 4, lc4 = (t & 15) * 4;
#pragma unroll
    for (int it = 0; it < 4; it++) {
        int r = lr + it * 16;
        float4 v = *(const float4*)&src[(size_t)(r0 + r) * C + c0 + lc4];
        tile[r][lc4 + 0] = v.x; tile[r][lc4 + 1] = v.y;
        tile[r][lc4 + 2] = v.z; tile[r][lc4 + 3] = v.w;
    }
    __syncthreads();
    int wc = t >> 2, wr8 = (t & 3) * 8;
#pragma unroll
    for (int it = 0; it < 2; it++) {
        int rr = wr8 + it * 32;
        bf16x8 o;
#pragma unroll
        for (int j = 0; j < 8; j++) o[j] = (bf16_t)tile[rr + j][wc];
        *(bf16x8*)&dst[(size_t)(c0 + wc) * R + r0 + rr] = o;
    }
}

// ---------------- transpose+cvt+interleave: build B_comb [4096][1024] per z ----------------
// comb row for w1 col c = (c>>4)*32 + (c&15); w3 -> +16.  z<9: w1-family, z>=9: w3-family.
__global__ __launch_bounds__(256) void transpose_comb9_kernel(
    const float* __restrict__ w1, const float* __restrict__ sw1,
    const float* __restrict__ w3, const float* __restrict__ sw3,
    bf16_t* __restrict__ outc) {
    __shared__ float tile[64][65];
    int zi = blockIdx.z;            // 0..17
    int is3 = zi >= 9;
    int zz = is3 ? zi - 9 : zi;
    const float* wsrc = is3 ? w3 : w1;
    const float* ssrc = is3 ? sw3 : sw1;
    const float* src = (zz < NEXP) ? (wsrc + (size_t)zz * DMODEL * HIDDEN) : ssrc;
    bf16_t* dst = outc + (size_t)zz * 4096 * DMODEL;
    int c0 = blockIdx.x * 64, r0 = blockIdx.y * 64;   // c over HIDDEN, r over DMODEL
    int t = threadIdx.x;
    int lr = t >> 4, lc4 = (t & 15) * 4;
#pragma unroll
    for (int it = 0; it < 4; it++) {
        int r = lr + it * 16;
        float4 v = *(const float4*)&src[(size_t)(r0 + r) * HIDDEN + c0 + lc4];
        tile[r][lc4 + 0] = v.x; tile[r][lc4 + 1] = v.y;
        tile[r][lc4 + 2] = v.z; tile[r][lc4 + 3] = v.w;
    }
    __syncthreads();
    int wc = t >> 2, wr8 = (t & 3) * 8;
    int c = c0 + wc;
    int rC = ((c >> 4) * 32) + (c & 15) + (is3 ? 16 : 0);
#pragma unroll
    for (int it = 0; it < 2; it++) {
        int rr = wr8 + it * 32;
        bf16x8 o;
#pragma unroll
        for (int j = 0; j < 8; j++) o[j] = (bf16_t)tile[rr + j][wc];
        *(bf16x8*)&dst[(size_t)rC * DMODEL + r0 + rr] = o;
    }
}

// single-expert variant for the fallback path: z=0 -> src1, z=1 -> src3; single output slab
__global__ __launch_bounds__(256) void transpose_comb1_kernel(
    const float* __restrict__ src1, const float* __restrict__ src3,
    bf16_t* __restrict__ outc) {
    __shared__ float tile[64][65];
    int is3 = blockIdx.z;
    const float* src = is3 ? src3 : src1;
    int c0 = blockIdx.x * 64, r0 = blockIdx.y * 64;
    int t = threadIdx.x;
    int lr = t >> 4, lc4 = (t & 15) * 4;
#pragma unroll
    for (int it = 0; it < 4; it++) {
        int r = lr + it * 16;
        float4 v = *(const float4*)&src[(size_t)(r0 + r) * HIDDEN + c0 + lc4];
        tile[r][lc4 + 0] = v.x; tile[r][lc4 + 1] = v.y;
        tile[r][lc4 + 2] = v.z; tile[r][lc4 + 3] = v.w;
    }
    __syncthreads();
    int wc = t >> 2, wr8 = (t & 3) * 8;
    int c = c0 + wc;
    int rC = ((c >> 4) * 32) + (c & 15) + (is3 ? 16 : 0);
#pragma unroll
    for (int it = 0; it < 2; it++) {
        int rr = wr8 + it * 32;
        bf16x8 o;
#pragma unroll
        for (int j = 0; j < 8; j++) o[j] = (bf16_t)tile[rr + j][wc];
        *(bf16x8*)&outc[(size_t)rC * DMODEL + r0 + rr] = o;
    }
}

// ---------------- GEMM1: act = silu(x@w1)*(x@w3), B_comb interleaved ----------------
// block 256m x 256n-comb, 8 waves (512 thr), wave tile 128m x 64n, BK=64,
// double-buffered 128 KiB LDS, counted vmcnt(8): next tile's loads span barriers.
__global__ __launch_bounds__(512, 1) void gemm1_kernel(
    const bf16_t* __restrict__ xb, const bf16_t* __restrict__ Bbase,
    const int* __restrict__ cnt, const int* __restrict__ tok,
    bf16_t* __restrict__ actbase, int z_base) {
    const int K = DMODEL;
    const int zl = blockIdx.z, z = z_base + zl;
    const int n0 = blockIdx.x * 256;      // combined col base
    const int m0 = blockIdx.y * 256;
    int nrow;
    const int* tokz = nullptr;
    if (z < NEXP) {
        int c = cnt[z];
        nrow = c < CAPA ? c : CAPA;
        if (m0 >= nrow) return;
        tokz = tok + (size_t)z * CAPA;
    } else {
        nrow = T_TOK;
    }
    const bf16_t* Bc = Bbase + (size_t)zl * 4096 * DMODEL;
    bf16_t* actp = actbase + (size_t)zl * CAPA * HIDDEN;

    __shared__ bf16_t sA[2][16384];  // [kc 8][m 256][k 8]  32 KB per buf
    __shared__ bf16_t sB[2][16384];
    const int tid = threadIdx.x, lane = tid & 63, w = tid >> 6;
    const int quad = lane >> 4, l16 = lane & 15;
    const int wm = (w >> 2) * 128, wn = (w & 3) * 64;

    // staging: 4 x 16B per thread per matrix; slot q = i*8+w -> kc=q>>2, 64-row range=(q&3)*64
    const bf16_t* ga[4]; const bf16_t* gb[4]; int loS[4];
#pragma unroll
    for (int i = 0; i < 4; i++) {
        int q = i * 8 + w;
        int c = q >> 2, base = (q & 3) * 64;
        int m = base + lane;
        int row;
        if (z < NEXP) { int slot = m0 + m; row = tokz[slot < nrow ? slot : 0]; }
        else row = m0 + m;
        ga[i] = xb + (size_t)row * K + c * 8;
        gb[i] = Bc + (size_t)(n0 + m) * K + c * 8;
        loS[i] = (c * 256 + base) * 8;
    }

    f32x4 acc[8][4];
#pragma unroll
    for (int i = 0; i < 8; i++)
#pragma unroll
        for (int j = 0; j < 4; j++) acc[i][j] = (f32x4)0.f;

    auto stage = [&](bf16_t* A, bf16_t* B, int ko) {
#pragma unroll
        for (int i = 0; i < 4; i++) {
            gl_lds16(ga[i] + ko, &A[loS[i]]);
            gl_lds16(gb[i] + ko, &B[loS[i]]);
        }
    };
    auto comp = [&](const bf16_t* A, const bf16_t* B) {
#pragma unroll
        for (int kk = 0; kk < 2; kk++) {
            bf16x8 af[8];
#pragma unroll
            for (int mi = 0; mi < 8; mi++)
                af[mi] = *(const bf16x8*)&A[((kk * 4 + quad) * 256 + wm + mi * 16 + l16) * 8];
#pragma unroll
            for (int nj = 0; nj < 4; nj++) {
                bf16x8 bfr = *(const bf16x8*)&B[((kk * 4 + quad) * 256 + wn + nj * 16 + l16) * 8];
#pragma unroll
                for (int mi = 0; mi < 8; mi++)
                    acc[mi][nj] = __builtin_amdgcn_mfma_f32_16x16x32_bf16(af[mi], bfr, acc[mi][nj], 0, 0, 0);
            }
        }
    };

    stage(sA[0], sB[0], 0);
    stage(sA[1], sB[1], 64);
    VMCNT8(); SCHED0(); BARRIER(); SCHED0();
    for (int k0 = 0; k0 < K; k0 += 128) {
        comp(sA[0], sB[0]);
        LGKM0(); SCHED0(); BARRIER(); SCHED0();
        if (k0 + 128 < K) { stage(sA[0], sB[0], k0 + 128); VMCNT8(); }
        else { VMCNT0(); }
        SCHED0(); BARRIER(); SCHED0();
        comp(sA[1], sB[1]);
        if (k0 + 128 >= K) break;
        LGKM0(); SCHED0(); BARRIER(); SCHED0();
        if (k0 + 192 < K) { stage(sA[1], sB[1], k0 + 192); VMCNT8(); }
        else { VMCNT0(); }
        SCHED0(); BARRIER(); SCHED0();
    }

    // epilogue: nj pairs (0,1) and (2,3) are (h1,h3) of the same 16 output cols
#pragma unroll
    for (int mi = 0; mi < 8; mi++)
#pragma unroll
        for (int p = 0; p < 2; p++)
#pragma unroll
            for (int r = 0; r < 4; r++) {
                int m = m0 + wm + mi * 16 + quad * 4 + r;
                if (z == NEXP || m < nrow) {
                    float h1 = acc[mi][2 * p][r], h3 = acc[mi][2 * p + 1][r];
                    float s = h1 / (1.f + __expf(-h1));
                    int nout = (n0 + wn) / 2 + p * 16 + l16;
                    actp[(size_t)m * HIDDEN + nout] = (bf16_t)(s * h3);
                }
            }
}

// ---------------- GEMM2 (merged): z<8 routed (gate*bf16 -> yr), z==8 shared (f32 -> outp)
// block 256m x 256n, 8 waves, wave 128m x 64n, BK=64, dbuf 128 KiB, counted vmcnt(8).
__global__ __launch_bounds__(512, 1) void gemm2_kernel(const bf16_t* __restrict__ Abase,
                                                       const bf16_t* __restrict__ Bbase,
                                                       const int* __restrict__ cnt,
                                                       const float* __restrict__ gate,
                                                       bf16_t* __restrict__ yr,
                                                       float* __restrict__ outp,
                                                       int z_base) {
    const int K = HIDDEN, N = DMODEL;
    const int zl = blockIdx.z, z = z_base + zl;
    const int n0 = blockIdx.x * 256, m0 = blockIdx.y * 256;
    int nrow;
    if (z < NEXP) {
        int c = cnt[z];
        nrow = c < CAPA ? c : CAPA;
        if (m0 >= nrow) return;
    } else {
        nrow = T_TOK;
    }
    const bf16_t* A = Abase + (size_t)zl * CAPA * HIDDEN;  // zl==8 -> shared slab
    const bf16_t* B = Bbase + (size_t)zl * DMODEL * HIDDEN;

    __shared__ bf16_t sA[2][16384];
    __shared__ bf16_t sB[2][16384];
    const int tid = threadIdx.x, lane = tid & 63, w = tid >> 6;
    const int quad = lane >> 4, l16 = lane & 15;
    const int wm = (w >> 2) * 128, wn = (w & 3) * 64;

    const bf16_t* ga[4]; const bf16_t* gb[4]; int loS[4];
#pragma unroll
    for (int i = 0; i < 4; i++) {
        int q = i * 8 + w;
        int c = q >> 2, base = (q & 3) * 64;
        int m = base + lane;
        ga[i] = A + (size_t)(m0 + m) * K + c * 8;
        gb[i] = B + (size_t)(n0 + m) * K + c * 8;
        loS[i] = (c * 256 + base) * 8;
    }

    f32x4 acc[8][4];
#pragma unroll
    for (int i = 0; i < 8; i++)
#pragma unroll
        for (int j = 0; j < 4; j++) acc[i][j] = (f32x4)0.f;

    auto stage = [&](bf16_t* SA, bf16_t* SB, int ko) {
#pragma unroll
        for (int i = 0; i < 4; i++) {
            gl_lds16(ga[i] + ko, &SA[loS[i]]);
            gl_lds16(gb[i] + ko, &SB[loS[i]]);
        }
    };
    auto comp = [&](const bf16_t* SA, const bf16_t* SB) {
#pragma unroll
        for (int kk = 0; kk < 2; kk++) {
            bf16x8 af[8];
#pragma unroll
            for (int mi = 0; mi < 8; mi++)
                af[mi] = *(const bf16x8*)&SA[((kk * 4 + quad) * 256 + wm + mi * 16 + l16) * 8];
#pragma unroll
            for (int nj = 0; nj < 4; nj++) {
                bf16x8 bfr = *(const bf16x8*)&SB[((kk * 4 + quad) * 256 + wn + nj * 16 + l16) * 8];
#pragma unroll
                for (int mi = 0; mi < 8; mi++)
                    acc[mi][nj] = __builtin_amdgcn_mfma_f32_16x16x32_bf16(af[mi], bfr, acc[mi][nj], 0, 0, 0);
            }
        }
    };

    stage(sA[0], sB[0], 0);
    stage(sA[1], sB[1], 64);
    VMCNT8(); SCHED0(); BARRIER(); SCHED0();
    for (int k0 = 0; k0 < K; k0 += 128) {
        comp(sA[0], sB[0]);
        LGKM0(); SCHED0(); BARRIER(); SCHED0();
        if (k0 + 128 < K) { stage(sA[0], sB[0], k0 + 128); VMCNT8(); }
        else { VMCNT0(); }
        SCHED0(); BARRIER(); SCHED0();
        comp(sA[1], sB[1]);
        if (k0 + 128 >= K) break;
        LGKM0(); SCHED0(); BARRIER(); SCHED0();
        if (k0 + 192 < K) { stage(sA[1], sB[1], k0 + 192); VMCNT8(); }
        else { VMCNT0(); }
        SCHED0(); BARRIER(); SCHED0();
    }

#pragma unroll
    for (int mi = 0; mi < 8; mi++)
#pragma unroll
        for (int r = 0; r < 4; r++) {
            int m = m0 + wm + mi * 16 + quad * 4 + r;
            if (z == NEXP) {
#pragma unroll
                for (int nj = 0; nj < 4; nj++) {
                    int n = n0 + wn + nj * 16 + l16;
                    outp[(size_t)m * N + n] = acc[mi][nj][r];
                }
            } else if (m < nrow) {
                float g = gate[(size_t)z * CAPA + m];
#pragma unroll
                for (int nj = 0; nj < 4; nj++) {
                    int n = n0 + wn + nj * 16 + l16;
                    yr[((size_t)z * CAPA + m) * N + n] = (bf16_t)(g * acc[mi][nj][r]);
                }
            }
        }
}

// ---------------- combine: out[t] += yr[p1] + yr[p2] ----------------
__global__ __launch_bounds__(256) void combine_kernel(const int2* __restrict__ pair,
                                                      const bf16_t* __restrict__ yr,
                                                      float* __restrict__ outp) {
    int t = blockIdx.x;
    int d = threadIdx.x * 4;
    int2 p = pair[t];
    float* op = outp + (size_t)t * DMODEL + d;
    float4 o = *(float4*)op;
    if (p.x >= 0) {
        const bf16_t* r = yr + (size_t)p.x * DMODEL + d;
        o.x += (float)r[0]; o.y += (float)r[1]; o.z += (float)r[2]; o.w += (float)r[3];
    }
    if (p.y >= 0) {
        const bf16_t* r = yr + (size_t)p.y * DMODEL + d;
        o.x += (float)r[0]; o.y += (float)r[1]; o.z += (float)r[2]; o.w += (float)r[3];
    }
    *(float4*)op = o;
}

extern "C" void kernel_launch(void* const* d_in, const int* in_sizes, int n_in,
                              void* d_out, int out_size, void* d_ws, size_t ws_size,
                              hipStream_t stream) {
    (void)in_sizes; (void)n_in; (void)out_size;
    const float* x   = (const float*)d_in[0];
    const float* wr  = (const float*)d_in[1];
    const float* w1  = (const float*)d_in[2];
    const float* w3  = (const float*)d_in[3];
    const float* w2  = (const float*)d_in[4];
    const float* sw1 = (const float*)d_in[5];
    const float* sw3 = (const float*)d_in[6];
    const float* sw2 = (const float*)d_in[7];
    float* outp = (float*)d_out;

    const size_t TD = (size_t)T_TOK * DMODEL;
    const size_t DH = (size_t)DMODEL * HIDDEN;
    auto al = [](size_t b) { return (b + 255) & ~(size_t)255; };

    char* p = (char*)d_ws;
    size_t off = 0;
    auto alloc = [&](size_t b) { char* r = p + off; off += al(b); return r; };

    int* cnt    = (int*)alloc(NEXP * 4);
    int* tok    = (int*)alloc((size_t)NEXP * CAPA * 4);
    float* gate = (float*)alloc((size_t)NEXP * CAPA * 4);
    int2* pairp = (int2*)alloc((size_t)T_TOK * 8);

    const size_t xb_b  = TD * 2;                                    // 8.39 MB
    const size_t yr_b  = (size_t)NEXP * CAPA * DMODEL * 2;          // 23.1 MB
    const size_t act_b = ((size_t)NEXP * CAPA + T_TOK) * HIDDEN * 2;// 62.9 MB
    const size_t wbc_b = (size_t)9 * 4096 * DMODEL * 2;             // 75.5 MB (interleaved w1|w3)
    const size_t wb2_b = 9 * DH * 2;                                // 37.7 MB

    size_t needA = off + al(wbc_b) + al(wb2_b) + al(act_b) + al(yr_b > xb_b ? yr_b : xb_b);
    if (ws_size >= needA) {
        // -------- batched path --------
        bf16_t* wbC = (bf16_t*)alloc(wbc_b);
        bf16_t* wb2 = (bf16_t*)alloc(wb2_b);
        bf16_t* act = (bf16_t*)alloc(act_b);
        char* region = alloc(yr_b > xb_b ? yr_b : xb_b);
        bf16_t* xb = (bf16_t*)region;   // lifetime: cvt .. gemm1
        bf16_t* yr = (bf16_t*)region;   // lifetime: gemm2 .. combine (after all xb reads)

        hipMemsetAsync(cnt, 0, NEXP * 4, stream);
        cvt_x_kernel<<<dim3((unsigned)(TD / 8 / 256)), 256, 0, stream>>>(x, xb, (int)(TD / 8));
        router_kernel<<<dim3(T_TOK / 4), 256, 0, stream>>>(x, wr, cnt, tok, gate, pairp);
        transpose_comb9_kernel<<<dim3(HIDDEN / 64, DMODEL / 64, 18), 256, 0, stream>>>(
            w1, sw1, w3, sw3, wbC);
        transpose_cvt_kernel<<<dim3(DMODEL / 64, HIDDEN / 64, 9), 256, 0, stream>>>(w2, sw2, wb2, HIDDEN, DMODEL);
        gemm1_kernel<<<dim3(16, T_TOK / 256, 9), 512, 0, stream>>>(xb, wbC, cnt, tok, act, 0);
        gemm2_kernel<<<dim3(DMODEL / 256, T_TOK / 256, 9), 512, 0, stream>>>(act, wb2, cnt, gate, yr, outp, 0);
        combine_kernel<<<dim3(T_TOK), 256, 0, stream>>>(pairp, yr, outp);
    } else {
        // -------- small-ws sequential fallback (no aliasing) --------
        bf16_t* xb   = (bf16_t*)alloc(xb_b);
        bf16_t* yr   = (bf16_t*)alloc(yr_b);
        bf16_t* wbC1 = (bf16_t*)alloc((size_t)4096 * DMODEL * 2);
        bf16_t* wb2f = (bf16_t*)alloc(DH * 2);
        bf16_t* act  = (bf16_t*)alloc((size_t)T_TOK * HIDDEN * 2);

        hipMemsetAsync(cnt, 0, NEXP * 4, stream);
        cvt_x_kernel<<<dim3((unsigned)(TD / 8 / 256)), 256, 0, stream>>>(x, xb, (int)(TD / 8));
        router_kernel<<<dim3(T_TOK / 4), 256, 0, stream>>>(x, wr, cnt, tok, gate, pairp);
        // shared expert
        transpose_comb1_kernel<<<dim3(HIDDEN / 64, DMODEL / 64, 2), 256, 0, stream>>>(sw1, sw3, wbC1);
        transpose_cvt_kernel<<<dim3(DMODEL / 64, HIDDEN / 64, 1), 256, 0, stream>>>(sw2, sw2, wb2f, HIDDEN, DMODEL);
        gemm1_kernel<<<dim3(16, T_TOK / 256, 1), 512, 0, stream>>>(xb, wbC1, cnt, tok, act, NEXP);
        gemm2_kernel<<<dim3(DMODEL / 256, T_TOK / 256, 1), 512, 0, stream>>>(act, wb2f, cnt, gate, yr, outp, NEXP);
        // routed experts
        for (int e = 0; e < NEXP; e++) {
            transpose_comb1_kernel<<<dim3(HIDDEN / 64, DMODEL / 64, 2), 256, 0, stream>>>(
                w1 + (size_t)e * DH, w3 + (size_t)e * DH, wbC1);
            transpose_cvt_kernel<<<dim3(DMODEL / 64, HIDDEN / 64, 1), 256, 0, stream>>>(
                w2 + (size_t)e * DH, sw2, wb2f, HIDDEN, DMODEL);
            gemm1_kernel<<<dim3(16, (CAPA + 255) / 256, 1), 512, 0, stream>>>(xb, wbC1, cnt, tok, act, e);
            gemm2_kernel<<<dim3(DMODEL / 256, (CAPA + 255) / 256, 1), 512, 0, stream>>>(act, wb2f, cnt, gate, yr, outp, e);
        }
        combine_kernel<<<dim3(T_TOK), 256, 0, stream>>>(pairp, yr, outp);
    }
}

// Round 4
// 792.530 us; speedup vs baseline: 1.0591x; 1.0591x over previous
//
#include <hip/hip_runtime.h>
#include <hip/hip_bf16.h>
#include <cstdint>
#include <cstddef>

#define T_TOK 4096
#define DMODEL 1024
#define HIDDEN 2048
#define NEXP 8     // routed experts; index 8 = shared
#define CAPA 1408  // per-expert slot capacity (mean load 1024, sd ~30)

typedef __bf16 bf16_t;
typedef bf16_t bf16x8 __attribute__((ext_vector_type(8)));
typedef float f32x4 __attribute__((ext_vector_type(4)));

#define LGKM0() asm volatile("s_waitcnt lgkmcnt(0)" ::: "memory")
#define VMCNT0() asm volatile("s_waitcnt vmcnt(0)" ::: "memory")
#define SCHED0() __builtin_amdgcn_sched_barrier(0)
#define BARRIER() __builtin_amdgcn_s_barrier()

// async global->LDS, 16B per lane; LDS dest = wave-uniform base + lane*16
__device__ __forceinline__ void gl_lds16(const void* g, void* l) {
    __builtin_amdgcn_global_load_lds(
        (const __attribute__((address_space(1))) unsigned int*)g,
        (__attribute__((address_space(3))) unsigned int*)l, 16, 0, 0);
}

// ---------------- x f32 -> bf16 (8 elts/thread, 16B stores) ----------------
__global__ __launch_bounds__(256) void cvt_x_kernel(const float* __restrict__ x,
                                                    bf16_t* __restrict__ xb, int n8) {
    int i = blockIdx.x * 256 + threadIdx.x;
    if (i >= n8) return;
    const float4* v = (const float4*)(x + (size_t)i * 8);
    float4 a = v[0], b = v[1];
    bf16x8 o = {(bf16_t)a.x, (bf16_t)a.y, (bf16_t)a.z, (bf16_t)a.w,
                (bf16_t)b.x, (bf16_t)b.y, (bf16_t)b.z, (bf16_t)b.w};
    *(bf16x8*)(xb + (size_t)i * 8) = o;
}

// ---------------- router: logits -> top2 -> expert lists + per-token pair ----------------
__global__ __launch_bounds__(256) void router_kernel(const float* __restrict__ x,
                                                     const float* __restrict__ wr,
                                                     int* __restrict__ cnt,
                                                     int* __restrict__ tok,
                                                     float* __restrict__ gate,
                                                     int2* __restrict__ pair) {
    int token = (blockIdx.x * 256 + threadIdx.x) >> 6;
    int lane = threadIdx.x & 63;
    if (token >= T_TOK) return;
    const float* xr = x + (size_t)token * DMODEL;
    float acc[8];
#pragma unroll
    for (int e = 0; e < 8; e++) acc[e] = 0.f;
    for (int d = lane; d < DMODEL; d += 64) {
        float xv = xr[d];
        const float* w = wr + d * 8;
#pragma unroll
        for (int e = 0; e < 8; e++) acc[e] += xv * w[e];
    }
#pragma unroll
    for (int e = 0; e < 8; e++) {
#pragma unroll
        for (int off = 32; off > 0; off >>= 1) acc[e] += __shfl_down(acc[e], off);
    }
    if (lane == 0) {
        int i1 = 0; float v1 = acc[0];
#pragma unroll
        for (int e = 1; e < 8; e++) if (acc[e] > v1) { v1 = acc[e]; i1 = e; }
        int i2 = -1; float v2 = -1e30f;
#pragma unroll
        for (int e = 0; e < 8; e++) if (e != i1 && acc[e] > v2) { v2 = acc[e]; i2 = e; }
        float g1 = 1.f / (1.f + __expf(v2 - v1));
        float g2 = 1.f - g1;
        int p1 = atomicAdd(&cnt[i1], 1);
        int px = -1, py = -1;
        if (p1 < CAPA) {
            tok[(size_t)i1 * CAPA + p1] = token; gate[(size_t)i1 * CAPA + p1] = g1;
            px = i1 * CAPA + p1;
        }
        int p2 = atomicAdd(&cnt[i2], 1);
        if (p2 < CAPA) {
            tok[(size_t)i2 * CAPA + p2] = token; gate[(size_t)i2 * CAPA + p2] = g2;
            py = i2 * CAPA + p2;
        }
        pair[token] = make_int2(px, py);
    }
}

// ---------------- transpose+cvt: f32 [R][C] -> bf16 [C][R], 64x64 tiles (for w2) ----------------
__global__ __launch_bounds__(256) void transpose_cvt_kernel(const float* __restrict__ w,
                                                            const float* __restrict__ sw,
                                                            bf16_t* __restrict__ out,
                                                            int R, int C) {
    __shared__ float tile[64][65];
    int z = blockIdx.z;
    const float* src = (z < NEXP) ? (w + (size_t)z * R * C) : sw;
    bf16_t* dst = out + (size_t)z * R * C;
    int c0 = blockIdx.x * 64, r0 = blockIdx.y * 64;
    int t = threadIdx.x;
    int lr = t >> 4, lc4 = (t & 15) * 4;
#pragma unroll
    for (int it = 0; it < 4; it++) {
        int r = lr + it * 16;
        float4 v = *(const float4*)&src[(size_t)(r0 + r) * C + c0 + lc4];
        tile[r][lc4 + 0] = v.x; tile[r][lc4 + 1] = v.y;
        tile[r][lc4 + 2] = v.z; tile[r][lc4 + 3] = v.w;
    }
    __syncthreads();
    int wc = t >> 2, wr8 = (t & 3) * 8;
#pragma unroll
    for (int it = 0; it < 2; it++) {
        int rr = wr8 + it * 32;
        bf16x8 o;
#pragma unroll
        for (int j = 0; j < 8; j++) o[j] = (bf16_t)tile[rr + j][wc];
        *(bf16x8*)&dst[(size_t)(c0 + wc) * R + r0 + rr] = o;
    }
}

// ---------------- transpose+cvt+interleave: build B_comb [4096][1024] per z ----------------
// comb row for w1 col c = (c>>4)*32 + (c&15); w3 -> +16.  z<9: w1-family, z>=9: w3-family.
__global__ __launch_bounds__(256) void transpose_comb9_kernel(
    const float* __restrict__ w1, const float* __restrict__ sw1,
    const float* __restrict__ w3, const float* __restrict__ sw3,
    bf16_t* __restrict__ outc) {
    __shared__ float tile[64][65];
    int zi = blockIdx.z;            // 0..17
    int is3 = zi >= 9;
    int zz = is3 ? zi - 9 : zi;
    const float* wsrc = is3 ? w3 : w1;
    const float* ssrc = is3 ? sw3 : sw1;
    const float* src = (zz < NEXP) ? (wsrc + (size_t)zz * DMODEL * HIDDEN) : ssrc;
    bf16_t* dst = outc + (size_t)zz * 4096 * DMODEL;
    int c0 = blockIdx.x * 64, r0 = blockIdx.y * 64;   // c over HIDDEN, r over DMODEL
    int t = threadIdx.x;
    int lr = t >> 4, lc4 = (t & 15) * 4;
#pragma unroll
    for (int it = 0; it < 4; it++) {
        int r = lr + it * 16;
        float4 v = *(const float4*)&src[(size_t)(r0 + r) * HIDDEN + c0 + lc4];
        tile[r][lc4 + 0] = v.x; tile[r][lc4 + 1] = v.y;
        tile[r][lc4 + 2] = v.z; tile[r][lc4 + 3] = v.w;
    }
    __syncthreads();
    int wc = t >> 2, wr8 = (t & 3) * 8;
    int c = c0 + wc;
    int rC = ((c >> 4) * 32) + (c & 15) + (is3 ? 16 : 0);
#pragma unroll
    for (int it = 0; it < 2; it++) {
        int rr = wr8 + it * 32;
        bf16x8 o;
#pragma unroll
        for (int j = 0; j < 8; j++) o[j] = (bf16_t)tile[rr + j][wc];
        *(bf16x8*)&dst[(size_t)rC * DMODEL + r0 + rr] = o;
    }
}

// single-expert variant for the fallback path: z=0 -> src1, z=1 -> src3; single output slab
__global__ __launch_bounds__(256) void transpose_comb1_kernel(
    const float* __restrict__ src1, const float* __restrict__ src3,
    bf16_t* __restrict__ outc) {
    __shared__ float tile[64][65];
    int is3 = blockIdx.z;
    const float* src = is3 ? src3 : src1;
    int c0 = blockIdx.x * 64, r0 = blockIdx.y * 64;
    int t = threadIdx.x;
    int lr = t >> 4, lc4 = (t & 15) * 4;
#pragma unroll
    for (int it = 0; it < 4; it++) {
        int r = lr + it * 16;
        float4 v = *(const float4*)&src[(size_t)(r0 + r) * HIDDEN + c0 + lc4];
        tile[r][lc4 + 0] = v.x; tile[r][lc4 + 1] = v.y;
        tile[r][lc4 + 2] = v.z; tile[r][lc4 + 3] = v.w;
    }
    __syncthreads();
    int wc = t >> 2, wr8 = (t & 3) * 8;
    int c = c0 + wc;
    int rC = ((c >> 4) * 32) + (c & 15) + (is3 ? 16 : 0);
#pragma unroll
    for (int it = 0; it < 2; it++) {
        int rr = wr8 + it * 32;
        bf16x8 o;
#pragma unroll
        for (int j = 0; j < 8; j++) o[j] = (bf16_t)tile[rr + j][wc];
        *(bf16x8*)&outc[(size_t)rC * DMODEL + r0 + rr] = o;
    }
}

// ---------------- GEMM1: act = silu(x@w1)*(x@w3), B_comb interleaved ----------------
// block 256m x 256n-comb, 8 waves (512 thr), wave tile 128m x 64n, K-tile 64.
// T3-minimum 2-phase: STAGE(next) -> comp(cur) -> lgkmcnt(0) -> vmcnt(0) -> ONE barrier.
__global__ __launch_bounds__(512, 1) void gemm1_kernel(
    const bf16_t* __restrict__ xb, const bf16_t* __restrict__ Bbase,
    const int* __restrict__ cnt, const int* __restrict__ tok,
    bf16_t* __restrict__ actbase, int z_base) {
    const int K = DMODEL;
    const int zl = blockIdx.z, z = z_base + zl;
    const int n0 = blockIdx.x * 256;      // combined col base
    const int m0 = blockIdx.y * 256;
    int nrow;
    const int* tokz = nullptr;
    if (z < NEXP) {
        int c = cnt[z];
        nrow = c < CAPA ? c : CAPA;
        if (m0 >= nrow) return;
        tokz = tok + (size_t)z * CAPA;
    } else {
        nrow = T_TOK;
    }
    const bf16_t* Bc = Bbase + (size_t)zl * 4096 * DMODEL;
    bf16_t* actp = actbase + (size_t)zl * CAPA * HIDDEN;

    __shared__ bf16_t sA[2][16384];  // [kc 8][m 256][8]  32 KB per buf
    __shared__ bf16_t sB[2][16384];
    const int tid = threadIdx.x, lane = tid & 63, w = tid >> 6;
    const int quad = lane >> 4, l16 = lane & 15;
    const int wm = (w >> 2) * 128, wn = (w & 3) * 64;

    // staging: 4 x 16B per thread per matrix; slot q = i*8+w -> kc=q>>2, 64-row range=(q&3)*64
    const bf16_t* ga[4]; const bf16_t* gb[4]; int loS[4];
#pragma unroll
    for (int i = 0; i < 4; i++) {
        int q = i * 8 + w;
        int c = q >> 2, base = (q & 3) * 64;
        int m = base + lane;
        int row;
        if (z < NEXP) { int slot = m0 + m; row = tokz[slot < nrow ? slot : 0]; }
        else row = m0 + m;
        ga[i] = xb + (size_t)row * K + c * 8;
        gb[i] = Bc + (size_t)(n0 + m) * K + c * 8;
        loS[i] = (c * 256 + base) * 8;
    }

    f32x4 acc[8][4];
#pragma unroll
    for (int i = 0; i < 8; i++)
#pragma unroll
        for (int j = 0; j < 4; j++) acc[i][j] = (f32x4)0.f;

    auto stage = [&](bf16_t* A, bf16_t* B, int ko) {
#pragma unroll
        for (int i = 0; i < 4; i++) {
            gl_lds16(ga[i] + ko, &A[loS[i]]);
            gl_lds16(gb[i] + ko, &B[loS[i]]);
        }
    };
    auto comp = [&](const bf16_t* A, const bf16_t* B) {
#pragma unroll
        for (int kk = 0; kk < 2; kk++) {
            bf16x8 af[8];
#pragma unroll
            for (int mi = 0; mi < 8; mi++)
                af[mi] = *(const bf16x8*)&A[((kk * 4 + quad) * 256 + wm + mi * 16 + l16) * 8];
#pragma unroll
            for (int nj = 0; nj < 4; nj++) {
                bf16x8 bfr = *(const bf16x8*)&B[((kk * 4 + quad) * 256 + wn + nj * 16 + l16) * 8];
#pragma unroll
                for (int mi = 0; mi < 8; mi++)
                    acc[mi][nj] = __builtin_amdgcn_mfma_f32_16x16x32_bf16(af[mi], bfr, acc[mi][nj], 0, 0, 0);
            }
        }
    };

    const int NT = K / 64;   // 16
    stage(sA[0], sB[0], 0);
    VMCNT0(); BARRIER();
    for (int t = 0; t < NT; t++) {
        int cur = t & 1;
        if (t + 1 < NT) stage(sA[cur ^ 1], sB[cur ^ 1], (t + 1) * 64);
        __builtin_amdgcn_s_setprio(1);
        comp(sA[cur], sB[cur]);
        __builtin_amdgcn_s_setprio(0);
        LGKM0(); SCHED0();
        VMCNT0();
        BARRIER();
    }

    // epilogue: nj pairs (0,1) and (2,3) are (h1,h3) of the same 16 output cols
#pragma unroll
    for (int mi = 0; mi < 8; mi++)
#pragma unroll
        for (int p = 0; p < 2; p++)
#pragma unroll
            for (int r = 0; r < 4; r++) {
                int m = m0 + wm + mi * 16 + quad * 4 + r;
                if (z == NEXP || m < nrow) {
                    float h1 = acc[mi][2 * p][r], h3 = acc[mi][2 * p + 1][r];
                    float s = h1 / (1.f + __expf(-h1));
                    int nout = (n0 + wn) / 2 + p * 16 + l16;
                    actp[(size_t)m * HIDDEN + nout] = (bf16_t)(s * h3);
                }
            }
}

// ---------------- GEMM2 (merged): z<8 routed (gate*bf16 -> yr), z==8 shared (f32 -> outp)
// tile 128x128, K-tile 64, 4 waves each 64x64; dbuf 64 KB, T3-minimum 1-barrier loop.
__global__ __launch_bounds__(256, 2) void gemm2_kernel(const bf16_t* __restrict__ Abase,
                                                       const bf16_t* __restrict__ Bbase,
                                                       const int* __restrict__ cnt,
                                                       const float* __restrict__ gate,
                                                       bf16_t* __restrict__ yr,
                                                       float* __restrict__ outp,
                                                       int z_base) {
    const int K = HIDDEN, N = DMODEL;
    const int zl = blockIdx.z, z = z_base + zl;
    const int n0 = blockIdx.x * 128, m0 = blockIdx.y * 128;
    int nrow;
    if (z < NEXP) {
        int c = cnt[z];
        nrow = c < CAPA ? c : CAPA;
        if (m0 >= nrow) return;
    } else {
        nrow = T_TOK;
    }
    const bf16_t* A = Abase + (size_t)zl * CAPA * HIDDEN;  // zl==8 -> shared slab
    const bf16_t* B = Bbase + (size_t)zl * DMODEL * HIDDEN;
    __shared__ bf16_t sA[2][8192];  // [kc 8][m 128][8] 16 KB per buf
    __shared__ bf16_t sB[2][8192];
    const int tid = threadIdx.x, lane = tid & 63, wave = tid >> 6;
    const int quad = lane >> 4, l16 = lane & 15;
    const int wm = (wave >> 1) * 64, wn = (wave & 1) * 64;
    const bf16_t* ga[4]; const bf16_t* gb[4]; int lo[4];
#pragma unroll
    for (int i = 0; i < 4; i++) {
        int cb = i * 4 + wave;            // 0..15
        int c = cb >> 1;                  // k-chunk 0..7
        int mrem = (cb & 1) * 64;
        int m = mrem + lane;
        ga[i] = A + (size_t)(m0 + m) * K + c * 8;
        gb[i] = B + (size_t)(n0 + m) * K + c * 8;
        lo[i] = (c * 128 + mrem) * 8;
    }
    f32x4 acc[4][4];
#pragma unroll
    for (int i = 0; i < 4; i++)
#pragma unroll
        for (int j = 0; j < 4; j++) acc[i][j] = (f32x4)0.f;

    auto stage = [&](bf16_t* SA, bf16_t* SB, int ko) {
#pragma unroll
        for (int i = 0; i < 4; i++) {
            gl_lds16(ga[i] + ko, &SA[lo[i]]);
            gl_lds16(gb[i] + ko, &SB[lo[i]]);
        }
    };
    auto comp = [&](const bf16_t* SA, const bf16_t* SB) {
#pragma unroll
        for (int kk = 0; kk < 2; kk++) {
            bf16x8 af[4];
#pragma unroll
            for (int t = 0; t < 4; t++)
                af[t] = *(const bf16x8*)&SA[((kk * 4 + quad) * 128 + wm + t * 16 + l16) * 8];
#pragma unroll
            for (int nj = 0; nj < 4; nj++) {
                bf16x8 bfr = *(const bf16x8*)&SB[((kk * 4 + quad) * 128 + wn + nj * 16 + l16) * 8];
#pragma unroll
                for (int mi = 0; mi < 4; mi++)
                    acc[mi][nj] = __builtin_amdgcn_mfma_f32_16x16x32_bf16(af[mi], bfr, acc[mi][nj], 0, 0, 0);
            }
        }
    };

    const int NT = K / 64;   // 32
    stage(sA[0], sB[0], 0);
    VMCNT0(); BARRIER();
    for (int t = 0; t < NT; t++) {
        int cur = t & 1;
        if (t + 1 < NT) stage(sA[cur ^ 1], sB[cur ^ 1], (t + 1) * 64);
        __builtin_amdgcn_s_setprio(1);
        comp(sA[cur], sB[cur]);
        __builtin_amdgcn_s_setprio(0);
        LGKM0(); SCHED0();
        VMCNT0();
        BARRIER();
    }

#pragma unroll
    for (int mi = 0; mi < 4; mi++)
#pragma unroll
        for (int r = 0; r < 4; r++) {
            int m = m0 + wm + mi * 16 + quad * 4 + r;
            if (z == NEXP) {
#pragma unroll
                for (int nj = 0; nj < 4; nj++) {
                    int n = n0 + wn + nj * 16 + l16;
                    outp[(size_t)m * N + n] = acc[mi][nj][r];
                }
            } else if (m < nrow) {
                float g = gate[(size_t)z * CAPA + m];
#pragma unroll
                for (int nj = 0; nj < 4; nj++) {
                    int n = n0 + wn + nj * 16 + l16;
                    yr[((size_t)z * CAPA + m) * N + n] = (bf16_t)(g * acc[mi][nj][r]);
                }
            }
        }
}

// ---------------- combine: out[t] += yr[p1] + yr[p2] ----------------
__global__ __launch_bounds__(256) void combine_kernel(const int2* __restrict__ pair,
                                                      const bf16_t* __restrict__ yr,
                                                      float* __restrict__ outp) {
    int t = blockIdx.x;
    int d = threadIdx.x * 4;
    int2 p = pair[t];
    float* op = outp + (size_t)t * DMODEL + d;
    float4 o = *(float4*)op;
    if (p.x >= 0) {
        const bf16_t* r = yr + (size_t)p.x * DMODEL + d;
        o.x += (float)r[0]; o.y += (float)r[1]; o.z += (float)r[2]; o.w += (float)r[3];
    }
    if (p.y >= 0) {
        const bf16_t* r = yr + (size_t)p.y * DMODEL + d;
        o.x += (float)r[0]; o.y += (float)r[1]; o.z += (float)r[2]; o.w += (float)r[3];
    }
    *(float4*)op = o;
}

extern "C" void kernel_launch(void* const* d_in, const int* in_sizes, int n_in,
                              void* d_out, int out_size, void* d_ws, size_t ws_size,
                              hipStream_t stream) {
    (void)in_sizes; (void)n_in; (void)out_size;
    const float* x   = (const float*)d_in[0];
    const float* wr  = (const float*)d_in[1];
    const float* w1  = (const float*)d_in[2];
    const float* w3  = (const float*)d_in[3];
    const float* w2  = (const float*)d_in[4];
    const float* sw1 = (const float*)d_in[5];
    const float* sw3 = (const float*)d_in[6];
    const float* sw2 = (const float*)d_in[7];
    float* outp = (float*)d_out;

    const size_t TD = (size_t)T_TOK * DMODEL;
    const size_t DH = (size_t)DMODEL * HIDDEN;
    auto al = [](size_t b) { return (b + 255) & ~(size_t)255; };

    char* p = (char*)d_ws;
    size_t off = 0;
    auto alloc = [&](size_t b) { char* r = p + off; off += al(b); return r; };

    int* cnt    = (int*)alloc(NEXP * 4);
    int* tok    = (int*)alloc((size_t)NEXP * CAPA * 4);
    float* gate = (float*)alloc((size_t)NEXP * CAPA * 4);
    int2* pairp = (int2*)alloc((size_t)T_TOK * 8);

    const size_t xb_b  = TD * 2;                                    // 8.39 MB
    const size_t yr_b  = (size_t)NEXP * CAPA * DMODEL * 2;          // 23.1 MB
    const size_t act_b = ((size_t)NEXP * CAPA + T_TOK) * HIDDEN * 2;// 62.9 MB
    const size_t wbc_b = (size_t)9 * 4096 * DMODEL * 2;             // 75.5 MB (interleaved w1|w3)
    const size_t wb2_b = 9 * DH * 2;                                // 37.7 MB

    size_t needA = off + al(wbc_b) + al(wb2_b) + al(act_b) + al(yr_b > xb_b ? yr_b : xb_b);
    if (ws_size >= needA) {
        // -------- batched path --------
        bf16_t* wbC = (bf16_t*)alloc(wbc_b);
        bf16_t* wb2 = (bf16_t*)alloc(wb2_b);
        bf16_t* act = (bf16_t*)alloc(act_b);
        char* region = alloc(yr_b > xb_b ? yr_b : xb_b);
        bf16_t* xb = (bf16_t*)region;   // lifetime: cvt .. gemm1
        bf16_t* yr = (bf16_t*)region;   // lifetime: gemm2 .. combine (after all xb reads)

        hipMemsetAsync(cnt, 0, NEXP * 4, stream);
        cvt_x_kernel<<<dim3((unsigned)(TD / 8 / 256)), 256, 0, stream>>>(x, xb, (int)(TD / 8));
        router_kernel<<<dim3(T_TOK / 4), 256, 0, stream>>>(x, wr, cnt, tok, gate, pairp);
        transpose_comb9_kernel<<<dim3(HIDDEN / 64, DMODEL / 64, 18), 256, 0, stream>>>(
            w1, sw1, w3, sw3, wbC);
        transpose_cvt_kernel<<<dim3(DMODEL / 64, HIDDEN / 64, 9), 256, 0, stream>>>(w2, sw2, wb2, HIDDEN, DMODEL);
        gemm1_kernel<<<dim3(16, T_TOK / 256, 9), 512, 0, stream>>>(xb, wbC, cnt, tok, act, 0);
        gemm2_kernel<<<dim3(DMODEL / 128, T_TOK / 128, 9), 256, 0, stream>>>(act, wb2, cnt, gate, yr, outp, 0);
        combine_kernel<<<dim3(T_TOK), 256, 0, stream>>>(pairp, yr, outp);
    } else {
        // -------- small-ws sequential fallback (no aliasing) --------
        bf16_t* xb   = (bf16_t*)alloc(xb_b);
        bf16_t* yr   = (bf16_t*)alloc(yr_b);
        bf16_t* wbC1 = (bf16_t*)alloc((size_t)4096 * DMODEL * 2);
        bf16_t* wb2f = (bf16_t*)alloc(DH * 2);
        bf16_t* act  = (bf16_t*)alloc((size_t)T_TOK * HIDDEN * 2);

        hipMemsetAsync(cnt, 0, NEXP * 4, stream);
        cvt_x_kernel<<<dim3((unsigned)(TD / 8 / 256)), 256, 0, stream>>>(x, xb, (int)(TD / 8));
        router_kernel<<<dim3(T_TOK / 4), 256, 0, stream>>>(x, wr, cnt, tok, gate, pairp);
        // shared expert (z_base = NEXP, zl = 0)
        transpose_comb1_kernel<<<dim3(HIDDEN / 64, DMODEL / 64, 2), 256, 0, stream>>>(sw1, sw3, wbC1);
        transpose_cvt_kernel<<<dim3(DMODEL / 64, HIDDEN / 64, 1), 256, 0, stream>>>(sw2, sw2, wb2f, HIDDEN, DMODEL);
        gemm1_kernel<<<dim3(16, T_TOK / 256, 1), 512, 0, stream>>>(xb, wbC1, cnt, tok, act, NEXP);
        gemm2_kernel<<<dim3(DMODEL / 128, T_TOK / 128, 1), 256, 0, stream>>>(act, wb2f, cnt, gate, yr, outp, NEXP);
        // routed experts
        for (int e = 0; e < NEXP; e++) {
            transpose_comb1_kernel<<<dim3(HIDDEN / 64, DMODEL / 64, 2), 256, 0, stream>>>(
                w1 + (size_t)e * DH, w3 + (size_t)e * DH, wbC1);
            transpose_cvt_kernel<<<dim3(DMODEL / 64, HIDDEN / 64, 1), 256, 0, stream>>>(
                w2 + (size_t)e * DH, sw2, wb2f, HIDDEN, DMODEL);
            gemm1_kernel<<<dim3(16, (CAPA + 255) / 256, 1), 512, 0, stream>>>(xb, wbC1, cnt, tok, act, e);
            gemm2_kernel<<<dim3(DMODEL / 128, (CAPA + 127) / 128, 1), 256, 0, stream>>>(act, wb2f, cnt, gate, yr, outp, e);
        }
        combine_kernel<<<dim3(T_TOK), 256, 0, stream>>>(pairp, yr, outp);
    }
}